// Round 1
// baseline (874.157 us; speedup 1.0000x reference)
//
#include <hip/hip_runtime.h>
#include <hip/hip_bf16.h>

#define S_DIM 4
#define N_PTS 4096
#define P_TOT (S_DIM * N_PTS)   // 16384
#define HID 64
#define KNB 16

// ---------------- Kernel 1: fused projections ----------------
// qpe = x@Wq + bq + pos@Wpe + bpe
// kpe = x@Wk + bk + pos@Wpe + bpe
// v   = x@Wv + bv
__global__ __launch_bounds__(256) void proj_kernel(
    const float* __restrict__ x, const float* __restrict__ pos,
    const float* __restrict__ Wq, const float* __restrict__ bq,
    const float* __restrict__ Wk, const float* __restrict__ bk,
    const float* __restrict__ Wv, const float* __restrict__ bv,
    const float* __restrict__ Wpe, const float* __restrict__ bpe,
    float* __restrict__ qpe, float* __restrict__ kpe, float* __restrict__ vout)
{
    int tid = threadIdx.x;
    int h = tid & 63;
    int pl = tid >> 6;                 // 0..3 point-in-block
    int g = blockIdx.x * 4 + pl;       // global point id

    __shared__ float xs[4][64];
    __shared__ float ps[4][3];
    xs[pl][h] = x[g * 64 + h];
    if (h < 3) ps[pl][h] = pos[g * 3 + h];
    __syncthreads();

    float aq = bq[h], ak = bk[h], av = bv[h];
    #pragma unroll
    for (int f = 0; f < 64; ++f) {
        float xf = xs[pl][f];
        aq = fmaf(xf, Wq[f * 64 + h], aq);
        ak = fmaf(xf, Wk[f * 64 + h], ak);
        av = fmaf(xf, Wv[f * 64 + h], av);
    }
    float pe = bpe[h];
    pe = fmaf(ps[pl][0], Wpe[0 * 64 + h], pe);
    pe = fmaf(ps[pl][1], Wpe[1 * 64 + h], pe);
    pe = fmaf(ps[pl][2], Wpe[2 * 64 + h], pe);

    qpe[g * 64 + h]  = aq + pe;
    kpe[g * 64 + h]  = ak + pe;
    vout[g * 64 + h] = av;
}

// ---------------- Kernel 2: top-16 nearest neighbors ----------------
// One thread per query point; pos[s] staged in LDS (SoA, broadcast reads).
// Strict '<' comparisons reproduce jax.lax.top_k stable tie-breaking
// (earlier index wins on equal distance).
__global__ __launch_bounds__(64) void topk_kernel(
    const float* __restrict__ pos, int* __restrict__ nb)
{
    __shared__ float px[N_PTS];
    __shared__ float py[N_PTS];
    __shared__ float pz[N_PTS];

    int s = blockIdx.x >> 6;                       // 64 blocks per s
    int n = ((blockIdx.x & 63) << 6) + threadIdx.x;
    const float* ps = pos + (size_t)s * N_PTS * 3;

    for (int m = threadIdx.x; m < N_PTS; m += 64) {
        px[m] = ps[m * 3 + 0];
        py[m] = ps[m * 3 + 1];
        pz[m] = ps[m * 3 + 2];
    }
    __syncthreads();

    float qx = px[n], qy = py[n], qz = pz[n];

    float best[KNB];
    int   bidx[KNB];
    #pragma unroll
    for (int i = 0; i < KNB; ++i) { best[i] = 1e30f; bidx[i] = 0; }

    for (int m = 0; m < N_PTS; ++m) {
        float dx = qx - px[m];
        float dy = qy - py[m];
        float dz = qz - pz[m];
        float d = dx * dx + dy * dy + dz * dz;
        if (d < best[KNB - 1]) {
            best[KNB - 1] = d;
            bidx[KNB - 1] = m;
            #pragma unroll
            for (int i = KNB - 1; i > 0; --i) {
                if (best[i] < best[i - 1]) {
                    float tf = best[i]; best[i] = best[i - 1]; best[i - 1] = tf;
                    int   ti = bidx[i]; bidx[i] = bidx[i - 1]; bidx[i - 1] = ti;
                }
            }
        }
    }

    int g = s * N_PTS + n;
    #pragma unroll
    for (int i = 0; i < KNB; ++i) nb[g * KNB + i] = bidx[i];
}

// ---------------- Kernel 3: neighbor attention + output proj ----------------
__global__ __launch_bounds__(256) void attn_kernel(
    const float* __restrict__ x, const float* __restrict__ pos,
    const float* __restrict__ Wpd, const float* __restrict__ bpd,
    const float* __restrict__ Wa, const float* __restrict__ ba,
    const float* __restrict__ Wo, const float* __restrict__ bo,
    const float* __restrict__ qpe, const float* __restrict__ kpe,
    const float* __restrict__ v, const int* __restrict__ nb,
    float* __restrict__ out)
{
    int tid = threadIdx.x;
    int h = tid & 63;
    int w = tid >> 6;
    int g = blockIdx.x * 4 + w;     // global point id
    int sbase = (g >> 12) << 12;    // s * 4096

    float qv = qpe[g * 64 + h];
    float wh = qv * Wa[h] * 0.125f;   // / sqrt(64)

    float xn = pos[g * 3 + 0];
    float yn = pos[g * 3 + 1];
    float zn = pos[g * 3 + 2];
    float wpd0 = Wpd[0 * 64 + h], wpd1 = Wpd[1 * 64 + h], wpd2 = Wpd[2 * 64 + h];
    float bpdh = bpd[h];

    int j[KNB];
    #pragma unroll
    for (int k = 0; k < KNB; ++k) j[k] = sbase + nb[g * KNB + k];

    float logit[KNB];
    #pragma unroll
    for (int k = 0; k < KNB; ++k) {
        int jj = j[k];
        float rx = pos[jj * 3 + 0] - xn;
        float ry = pos[jj * 3 + 1] - yn;
        float rz = pos[jj * 3 + 2] - zn;
        float pd = bpdh;
        pd = fmaf(rx, wpd0, pd);
        pd = fmaf(ry, wpd1, pd);
        pd = fmaf(rz, wpd2, pd);
        float vec = kpe[jj * 64 + h] + pd;
        float t = wh * vec;
        #pragma unroll
        for (int off = 32; off >= 1; off >>= 1)
            t += __shfl_xor(t, off, 64);
        logit[k] = t;
    }

    float ba0 = ba[0];
    float mx = -1e30f;
    #pragma unroll
    for (int k = 0; k < KNB; ++k) { logit[k] += ba0; mx = fmaxf(mx, logit[k]); }
    float sum = 0.f;
    #pragma unroll
    for (int k = 0; k < KNB; ++k) { logit[k] = expf(logit[k] - mx); sum += logit[k]; }
    float inv = 1.0f / sum;

    float oh = 0.f;
    #pragma unroll
    for (int k = 0; k < KNB; ++k) oh = fmaf(logit[k], v[j[k] * 64 + h], oh);
    oh *= inv;

    // y_f = bo[f] + sum_h oh[h] * Wo[h][f]   (lane == f)
    float y = bo[h];
    #pragma unroll
    for (int hh = 0; hh < 64; ++hh) {
        float o = __shfl(oh, hh, 64);
        y = fmaf(o, Wo[hh * 64 + h], y);
    }

    // tanh-approx GELU (JAX default approximate=True)
    float t3 = y + 0.044715f * y * y * y;
    float ge = 0.5f * y * (1.0f + tanhf(0.7978845608028654f * t3));

    out[g * 64 + h] = x[g * 64 + h] + ge;
}

extern "C" void kernel_launch(void* const* d_in, const int* in_sizes, int n_in,
                              void* d_out, int out_size, void* d_ws, size_t ws_size,
                              hipStream_t stream) {
    const float* x   = (const float*)d_in[0];
    const float* pos = (const float*)d_in[1];
    const float* Wq  = (const float*)d_in[2];
    const float* bq  = (const float*)d_in[3];
    const float* Wk  = (const float*)d_in[4];
    const float* bk  = (const float*)d_in[5];
    const float* Wv  = (const float*)d_in[6];
    const float* bv  = (const float*)d_in[7];
    const float* Wpe = (const float*)d_in[8];
    const float* bpe = (const float*)d_in[9];
    const float* Wpd = (const float*)d_in[10];
    const float* bpd = (const float*)d_in[11];
    const float* Wa  = (const float*)d_in[12];
    const float* ba  = (const float*)d_in[13];
    const float* Wo  = (const float*)d_in[14];
    const float* bo  = (const float*)d_in[15];
    float* out = (float*)d_out;

    float* ws  = (float*)d_ws;
    float* qpe = ws;
    float* kpe = ws + (size_t)P_TOT * 64;
    float* vv  = ws + (size_t)2 * P_TOT * 64;
    int*   nbp = (int*)(ws + (size_t)3 * P_TOT * 64);

    proj_kernel<<<P_TOT / 4, 256, 0, stream>>>(x, pos, Wq, bq, Wk, bk, Wv, bv,
                                               Wpe, bpe, qpe, kpe, vv);
    topk_kernel<<<256, 64, 0, stream>>>(pos, nbp);
    attn_kernel<<<P_TOT / 4, 256, 0, stream>>>(x, pos, Wpd, bpd, Wa, ba, Wo, bo,
                                               qpe, kpe, vv, nbp, out);
}

// Round 2
// 274.304 us; speedup vs baseline: 3.1868x; 3.1868x over previous
//
#include <hip/hip_runtime.h>
#include <hip/hip_bf16.h>

#define S_DIM 4
#define N_PTS 4096
#define P_TOT (S_DIM * N_PTS)   // 16384
#define HID 64
#define KNB 16

// ---------------- Kernel 1: fused projections ----------------
__global__ __launch_bounds__(256) void proj_kernel(
    const float* __restrict__ x, const float* __restrict__ pos,
    const float* __restrict__ Wq, const float* __restrict__ bq,
    const float* __restrict__ Wk, const float* __restrict__ bk,
    const float* __restrict__ Wv, const float* __restrict__ bv,
    const float* __restrict__ Wpe, const float* __restrict__ bpe,
    float* __restrict__ qpe, float* __restrict__ kpe, float* __restrict__ vout)
{
    int tid = threadIdx.x;
    int h = tid & 63;
    int pl = tid >> 6;                 // 0..3 point-in-block
    int g = blockIdx.x * 4 + pl;       // global point id

    __shared__ float xs[4][64];
    __shared__ float ps[4][3];
    xs[pl][h] = x[g * 64 + h];
    if (h < 3) ps[pl][h] = pos[g * 3 + h];
    __syncthreads();

    float aq = bq[h], ak = bk[h], av = bv[h];
    #pragma unroll
    for (int f = 0; f < 64; ++f) {
        float xf = xs[pl][f];
        aq = fmaf(xf, Wq[f * 64 + h], aq);
        ak = fmaf(xf, Wk[f * 64 + h], ak);
        av = fmaf(xf, Wv[f * 64 + h], av);
    }
    float pe = bpe[h];
    pe = fmaf(ps[pl][0], Wpe[0 * 64 + h], pe);
    pe = fmaf(ps[pl][1], Wpe[1 * 64 + h], pe);
    pe = fmaf(ps[pl][2], Wpe[2 * 64 + h], pe);

    qpe[g * 64 + h]  = aq + pe;
    kpe[g * 64 + h]  = ak + pe;
    vout[g * 64 + h] = av;
}

// ---------------- Kernel 2: top-16 nearest neighbors ----------------
// One WAVE per query. Each lane scans 64 lane-strided candidates keeping a
// sorted top-16 of u64 keys (dist_bits<<32 | idx); keys are unique and give
// exact jax.lax.top_k tie-breaking (lower index wins on equal distance).
// Final: 16 rounds of wave-wide u64-min butterfly extraction.
__global__ __launch_bounds__(1024) void topk_kernel(
    const float* __restrict__ pos, int* __restrict__ nb)
{
    __shared__ __align__(16) float px[N_PTS];
    __shared__ __align__(16) float py[N_PTS];
    __shared__ __align__(16) float pz[N_PTS];

    int tid = threadIdx.x;
    int s = blockIdx.x >> 8;                 // 256 blocks per scene
    const float* ps = pos + (size_t)s * N_PTS * 3;

    // stage: thread t loads points 4t..4t+3 (3 coalesced float4 = 12 floats)
    {
        const float4* g4 = (const float4*)ps;
        float4 a = g4[tid * 3 + 0];   // p0.x p0.y p0.z p1.x
        float4 b = g4[tid * 3 + 1];   // p1.y p1.z p2.x p2.y
        float4 c = g4[tid * 3 + 2];   // p2.z p3.x p3.y p3.z
        ((float4*)px)[tid] = make_float4(a.x, a.w, b.z, c.y);
        ((float4*)py)[tid] = make_float4(a.y, b.x, b.w, c.z);
        ((float4*)pz)[tid] = make_float4(a.z, b.y, c.x, c.w);
    }
    __syncthreads();

    int wave = tid >> 6;
    int lane = tid & 63;
    int nloc = ((blockIdx.x & 255) << 4) + wave;   // query within scene

    float qx = px[nloc], qy = py[nloc], qz = pz[nloc];

    unsigned long long L[KNB];
    #pragma unroll
    for (int i = 0; i < KNB; ++i) L[i] = 0xFFFFFFFFFFFFFFFFull;

    for (int c = 0; c < 64; ++c) {
        int m = (c << 6) + lane;
        float dx = qx - px[m];
        float dy = qy - py[m];
        float dz = qz - pz[m];
        float d = dx * dx + dy * dy + dz * dz;
        unsigned long long key =
            ((unsigned long long)__float_as_uint(d) << 32) | (unsigned)m;
        if (key < L[KNB - 1]) {
            L[KNB - 1] = key;
            #pragma unroll
            for (int i = KNB - 1; i > 0; --i) {
                bool sw = L[i] < L[i - 1];
                unsigned long long lo = sw ? L[i] : L[i - 1];
                unsigned long long hi = sw ? L[i - 1] : L[i];
                L[i - 1] = lo;
                L[i] = hi;
            }
        }
    }

    // merge: extract global min 16 times
    unsigned long long cur = L[0];
    int res = 0;
    #pragma unroll
    for (int r = 0; r < KNB; ++r) {
        unsigned long long mn = cur;
        #pragma unroll
        for (int off = 32; off >= 1; off >>= 1) {
            unsigned long long o = __shfl_xor(mn, off, 64);
            mn = (o < mn) ? o : mn;
        }
        if (lane == r) res = (int)(unsigned)mn;   // low 32 bits = index
        bool pop = (cur == mn);                   // unique keys: exactly one lane
        #pragma unroll
        for (int i = 0; i < KNB - 1; ++i) L[i] = pop ? L[i + 1] : L[i];
        L[KNB - 1] = pop ? 0xFFFFFFFFFFFFFFFFull : L[KNB - 1];
        cur = L[0];
    }

    int g = (s << 12) + nloc;
    if (lane < KNB) nb[g * KNB + lane] = res;
}

// ---------------- Kernel 3: neighbor attention + output proj ----------------
__global__ __launch_bounds__(256) void attn_kernel(
    const float* __restrict__ x, const float* __restrict__ pos,
    const float* __restrict__ Wpd, const float* __restrict__ bpd,
    const float* __restrict__ Wa, const float* __restrict__ ba,
    const float* __restrict__ Wo, const float* __restrict__ bo,
    const float* __restrict__ qpe, const float* __restrict__ kpe,
    const float* __restrict__ v, const int* __restrict__ nb,
    float* __restrict__ out)
{
    int tid = threadIdx.x;
    int h = tid & 63;
    int w = tid >> 6;
    int g = blockIdx.x * 4 + w;     // global point id
    int sbase = (g >> 12) << 12;    // s * 4096

    float qv = qpe[g * 64 + h];
    float wh = qv * Wa[h] * 0.125f;   // / sqrt(64)

    float xn = pos[g * 3 + 0];
    float yn = pos[g * 3 + 1];
    float zn = pos[g * 3 + 2];
    float wpd0 = Wpd[0 * 64 + h], wpd1 = Wpd[1 * 64 + h], wpd2 = Wpd[2 * 64 + h];
    float bpdh = bpd[h];

    int j[KNB];
    #pragma unroll
    for (int k = 0; k < KNB; ++k) j[k] = sbase + nb[g * KNB + k];

    float logit[KNB];
    #pragma unroll
    for (int k = 0; k < KNB; ++k) {
        int jj = j[k];
        float rx = pos[jj * 3 + 0] - xn;
        float ry = pos[jj * 3 + 1] - yn;
        float rz = pos[jj * 3 + 2] - zn;
        float pd = bpdh;
        pd = fmaf(rx, wpd0, pd);
        pd = fmaf(ry, wpd1, pd);
        pd = fmaf(rz, wpd2, pd);
        float vec = kpe[jj * 64 + h] + pd;
        float t = wh * vec;
        #pragma unroll
        for (int off = 32; off >= 1; off >>= 1)
            t += __shfl_xor(t, off, 64);
        logit[k] = t;
    }

    float ba0 = ba[0];
    float mx = -1e30f;
    #pragma unroll
    for (int k = 0; k < KNB; ++k) { logit[k] += ba0; mx = fmaxf(mx, logit[k]); }
    float sum = 0.f;
    #pragma unroll
    for (int k = 0; k < KNB; ++k) { logit[k] = expf(logit[k] - mx); sum += logit[k]; }
    float inv = 1.0f / sum;

    float oh = 0.f;
    #pragma unroll
    for (int k = 0; k < KNB; ++k) oh = fmaf(logit[k], v[j[k] * 64 + h], oh);
    oh *= inv;

    // y_f = bo[f] + sum_h oh[h] * Wo[h][f]   (lane == f)
    float y = bo[h];
    #pragma unroll
    for (int hh = 0; hh < 64; ++hh) {
        float o = __shfl(oh, hh, 64);
        y = fmaf(o, Wo[hh * 64 + h], y);
    }

    // tanh-approx GELU (JAX default approximate=True)
    float t3 = y + 0.044715f * y * y * y;
    float ge = 0.5f * y * (1.0f + tanhf(0.7978845608028654f * t3));

    out[g * 64 + h] = x[g * 64 + h] + ge;
}

extern "C" void kernel_launch(void* const* d_in, const int* in_sizes, int n_in,
                              void* d_out, int out_size, void* d_ws, size_t ws_size,
                              hipStream_t stream) {
    const float* x   = (const float*)d_in[0];
    const float* pos = (const float*)d_in[1];
    const float* Wq  = (const float*)d_in[2];
    const float* bq  = (const float*)d_in[3];
    const float* Wk  = (const float*)d_in[4];
    const float* bk  = (const float*)d_in[5];
    const float* Wv  = (const float*)d_in[6];
    const float* bv  = (const float*)d_in[7];
    const float* Wpe = (const float*)d_in[8];
    const float* bpe = (const float*)d_in[9];
    const float* Wpd = (const float*)d_in[10];
    const float* bpd = (const float*)d_in[11];
    const float* Wa  = (const float*)d_in[12];
    const float* ba  = (const float*)d_in[13];
    const float* Wo  = (const float*)d_in[14];
    const float* bo  = (const float*)d_in[15];
    float* out = (float*)d_out;

    float* ws  = (float*)d_ws;
    float* qpe = ws;
    float* kpe = ws + (size_t)P_TOT * 64;
    float* vv  = ws + (size_t)2 * P_TOT * 64;
    int*   nbp = (int*)(ws + (size_t)3 * P_TOT * 64);

    proj_kernel<<<P_TOT / 4, 256, 0, stream>>>(x, pos, Wq, bq, Wk, bk, Wv, bv,
                                               Wpe, bpe, qpe, kpe, vv);
    topk_kernel<<<P_TOT / 16, 1024, 0, stream>>>(pos, nbp);
    attn_kernel<<<P_TOT / 4, 256, 0, stream>>>(x, pos, Wpd, bpd, Wa, ba, Wo, bo,
                                               qpe, kpe, vv, nbp, out);
}

// Round 3
// 111.381 us; speedup vs baseline: 7.8483x; 2.4627x over previous
//
#include <hip/hip_runtime.h>
#include <hip/hip_bf16.h>

#define S_DIM 4
#define N_PTS 4096
#define P_TOT (S_DIM * N_PTS)   // 16384
#define HID 64
#define KNB 16

#define GRID_G 8
#define CELL_H 0.125f
#define CAP 448                  // per-wave candidate buffer (LDS)

// ---------------- Kernel 1: fused projections ----------------
__global__ __launch_bounds__(256) void proj_kernel(
    const float* __restrict__ x, const float* __restrict__ pos,
    const float* __restrict__ Wq, const float* __restrict__ bq,
    const float* __restrict__ Wk, const float* __restrict__ bk,
    const float* __restrict__ Wv, const float* __restrict__ bv,
    const float* __restrict__ Wpe, const float* __restrict__ bpe,
    float* __restrict__ qpe, float* __restrict__ kpe, float* __restrict__ vout)
{
    int tid = threadIdx.x;
    int h = tid & 63;
    int pl = tid >> 6;
    int g = blockIdx.x * 4 + pl;

    __shared__ float xs[4][64];
    __shared__ float ps[4][3];
    xs[pl][h] = x[g * 64 + h];
    if (h < 3) ps[pl][h] = pos[g * 3 + h];
    __syncthreads();

    float aq = bq[h], ak = bk[h], av = bv[h];
    #pragma unroll
    for (int f = 0; f < 64; ++f) {
        float xf = xs[pl][f];
        aq = fmaf(xf, Wq[f * 64 + h], aq);
        ak = fmaf(xf, Wk[f * 64 + h], ak);
        av = fmaf(xf, Wv[f * 64 + h], av);
    }
    float pe = bpe[h];
    pe = fmaf(ps[pl][0], Wpe[0 * 64 + h], pe);
    pe = fmaf(ps[pl][1], Wpe[1 * 64 + h], pe);
    pe = fmaf(ps[pl][2], Wpe[2 * 64 + h], pe);

    qpe[g * 64 + h]  = aq + pe;
    kpe[g * 64 + h]  = ak + pe;
    vout[g * 64 + h] = av;
}

// ---------------- Kernel 1b: build 8^3 cell grid per scene ----------------
// One block per scene. cell id = (cx*8+cy)*8+cz (cz contiguous).
// gpts[slot] = {x, y, z, bits(orig_idx)} gathered cell-contiguously.
__global__ __launch_bounds__(1024) void grid_build(
    const float* __restrict__ pos, int* __restrict__ cell_start,
    float4* __restrict__ gpts)
{
    int s = blockIdx.x;
    int tid = threadIdx.x;
    const float* ps = pos + (size_t)s * N_PTS * 3;

    __shared__ int cnt[512];
    __shared__ int cur[512];
    __shared__ int sa[512];
    __shared__ int sb[512];
    __shared__ int start[513];

    if (tid < 512) { cnt[tid] = 0; cur[tid] = 0; }
    __syncthreads();

    // thread t owns points 4t..4t+3 (3 coalesced float4 loads)
    const float4* g4 = (const float4*)ps;
    float4 a = g4[tid * 3 + 0];
    float4 b = g4[tid * 3 + 1];
    float4 c4 = g4[tid * 3 + 2];
    float xx[4] = {a.x, a.w, b.z, c4.y};
    float yy[4] = {a.y, b.x, b.w, c4.z};
    float zz[4] = {a.z, b.y, c4.x, c4.w};
    int cell[4];
    #pragma unroll
    for (int k = 0; k < 4; ++k) {
        int cx = min(7, max(0, (int)(xx[k] * 8.0f)));
        int cy = min(7, max(0, (int)(yy[k] * 8.0f)));
        int cz = min(7, max(0, (int)(zz[k] * 8.0f)));
        cell[k] = (cx * 8 + cy) * 8 + cz;
        atomicAdd(&cnt[cell[k]], 1);
    }
    __syncthreads();

    // Hillis-Steele inclusive scan of cnt -> (sa or sb)
    if (tid < 512) sa[tid] = cnt[tid];
    __syncthreads();
    int* src = sa; int* dst = sb;
    for (int off = 1; off < 512; off <<= 1) {
        if (tid < 512) dst[tid] = src[tid] + ((tid >= off) ? src[tid - off] : 0);
        __syncthreads();
        int* t = src; src = dst; dst = t;
    }
    if (tid < 512) start[tid] = src[tid] - cnt[tid];   // exclusive
    if (tid == 0) start[512] = N_PTS;
    __syncthreads();

    if (tid < 513) cell_start[s * 513 + tid] = start[tid];

    #pragma unroll
    for (int k = 0; k < 4; ++k) {
        int slot = start[cell[k]] + atomicAdd(&cur[cell[k]], 1);
        gpts[(size_t)s * N_PTS + slot] =
            make_float4(xx[k], yy[k], zz[k], __uint_as_float((unsigned)(tid * 4 + k)));
    }
}

// ---------------- Kernel 2: exact top-16 via grid ----------------
// One wave per query. Scan the (2D+1)^3 cell block around the query's cell,
// ballot-compact candidates with d < (D*h)^2 into LDS. Geometry: any point
// with d < (D*h)^2 lies within Chebyshev cell distance D, so if >=16 survive
// the compacted set contains the exact top-16; else D++ and rescan.
// Keys (dist_bits<<32 | idx) are unique and reproduce jax.lax.top_k ordering.
__global__ __launch_bounds__(1024) void topk_kernel(
    const float* __restrict__ pos, const int* __restrict__ cell_start,
    const float4* __restrict__ gpts, int* __restrict__ nb)
{
    __shared__ unsigned long long buf[16][CAP];

    int tid = threadIdx.x;
    int wave = tid >> 6, lane = tid & 63;
    int g = blockIdx.x * 16 + wave;
    int s = g >> 12;
    const int* cs = cell_start + s * 513;
    const float4* gp = gpts + (size_t)s * N_PTS;
    unsigned long long* mybuf = buf[wave];

    float qx = pos[g * 3 + 0];
    float qy = pos[g * 3 + 1];
    float qz = pos[g * 3 + 2];
    int cx = min(7, max(0, (int)(qx * 8.0f)));
    int cy = min(7, max(0, (int)(qy * 8.0f)));
    int cz = min(7, max(0, (int)(qz * 8.0f)));

    unsigned long long lanemask_lt = (lane == 0) ? 0ull : (~0ull >> (64 - lane));

    int cnt = 0;
    int D = 1;
    while (true) {
        int xlo = max(cx - D, 0), xhi = min(cx + D, 7);
        int ylo = max(cy - D, 0), yhi = min(cy + D, 7);
        int zlo = max(cz - D, 0), zhi = min(cz + D, 7);
        bool full = (xlo == 0 && ylo == 0 && zlo == 0 &&
                     xhi == 7 && yhi == 7 && zhi == 7);
        float r = (float)D * CELL_H;
        float B = full ? __int_as_float(0x7f800000) : r * r;
        cnt = 0;
        for (int ix = xlo; ix <= xhi; ++ix) {
            for (int iy = ylo; iy <= yhi; ++iy) {
                int base = (ix * 8 + iy) * 8;
                int lo = cs[base + zlo];
                int hi = cs[base + zhi + 1];
                for (int bb = lo; bb < hi; bb += 64) {
                    int i = bb + lane;
                    bool act = i < hi;
                    float4 p = gp[act ? i : lo];
                    float dx = qx - p.x, dy = qy - p.y, dz = qz - p.z;
                    float d = fmaf(dx, dx, fmaf(dy, dy, dz * dz));
                    bool pred = act && (d < B);
                    unsigned long long m = __ballot(pred);
                    if (pred) {
                        int slot = cnt + __popcll(m & lanemask_lt);
                        if (slot < CAP)
                            mybuf[slot] =
                                ((unsigned long long)__float_as_uint(d) << 32) |
                                (unsigned long long)__float_as_uint(p.w);
                    }
                    cnt += __popcll(m);
                }
            }
        }
        if (cnt >= KNB || full) break;
        ++D;
    }
    cnt = min(cnt, CAP);

    // rank-count selection: rank = #{keys < mine}; unique keys -> exact order
    for (int bb = 0; bb < cnt; bb += 64) {
        int slot = bb + lane;
        unsigned long long my = (slot < cnt) ? mybuf[slot] : ~0ull;
        int rank = 0;
        for (int j = 0; j < cnt; ++j)
            rank += (mybuf[j] < my) ? 1 : 0;
        if (slot < cnt && rank < KNB)
            nb[(size_t)g * KNB + rank] = (int)(unsigned)(my & 0xFFFFFFFFull);
    }
}

// ---------------- Kernel 3: neighbor attention + output proj ----------------
__global__ __launch_bounds__(256) void attn_kernel(
    const float* __restrict__ x, const float* __restrict__ pos,
    const float* __restrict__ Wpd, const float* __restrict__ bpd,
    const float* __restrict__ Wa, const float* __restrict__ ba,
    const float* __restrict__ Wo, const float* __restrict__ bo,
    const float* __restrict__ qpe, const float* __restrict__ kpe,
    const float* __restrict__ v, const int* __restrict__ nb,
    float* __restrict__ out)
{
    int tid = threadIdx.x;
    int h = tid & 63;
    int w = tid >> 6;
    int g = blockIdx.x * 4 + w;
    int sbase = (g >> 12) << 12;

    float qv = qpe[g * 64 + h];
    float wh = qv * Wa[h] * 0.125f;

    float xn = pos[g * 3 + 0];
    float yn = pos[g * 3 + 1];
    float zn = pos[g * 3 + 2];
    float wpd0 = Wpd[0 * 64 + h], wpd1 = Wpd[1 * 64 + h], wpd2 = Wpd[2 * 64 + h];
    float bpdh = bpd[h];

    int j[KNB];
    #pragma unroll
    for (int k = 0; k < KNB; ++k) j[k] = sbase + nb[g * KNB + k];

    float logit[KNB];
    #pragma unroll
    for (int k = 0; k < KNB; ++k) {
        int jj = j[k];
        float rx = pos[jj * 3 + 0] - xn;
        float ry = pos[jj * 3 + 1] - yn;
        float rz = pos[jj * 3 + 2] - zn;
        float pd = bpdh;
        pd = fmaf(rx, wpd0, pd);
        pd = fmaf(ry, wpd1, pd);
        pd = fmaf(rz, wpd2, pd);
        float vec = kpe[jj * 64 + h] + pd;
        float t = wh * vec;
        #pragma unroll
        for (int off = 32; off >= 1; off >>= 1)
            t += __shfl_xor(t, off, 64);
        logit[k] = t;
    }

    float ba0 = ba[0];
    float mx = -1e30f;
    #pragma unroll
    for (int k = 0; k < KNB; ++k) { logit[k] += ba0; mx = fmaxf(mx, logit[k]); }
    float sum = 0.f;
    #pragma unroll
    for (int k = 0; k < KNB; ++k) { logit[k] = expf(logit[k] - mx); sum += logit[k]; }
    float inv = 1.0f / sum;

    float oh = 0.f;
    #pragma unroll
    for (int k = 0; k < KNB; ++k) oh = fmaf(logit[k], v[j[k] * 64 + h], oh);
    oh *= inv;

    float y = bo[h];
    #pragma unroll
    for (int hh = 0; hh < 64; ++hh) {
        float o = __shfl(oh, hh, 64);
        y = fmaf(o, Wo[hh * 64 + h], y);
    }

    float t3 = y + 0.044715f * y * y * y;
    float ge = 0.5f * y * (1.0f + tanhf(0.7978845608028654f * t3));

    out[g * 64 + h] = x[g * 64 + h] + ge;
}

extern "C" void kernel_launch(void* const* d_in, const int* in_sizes, int n_in,
                              void* d_out, int out_size, void* d_ws, size_t ws_size,
                              hipStream_t stream) {
    const float* x   = (const float*)d_in[0];
    const float* pos = (const float*)d_in[1];
    const float* Wq  = (const float*)d_in[2];
    const float* bq  = (const float*)d_in[3];
    const float* Wk  = (const float*)d_in[4];
    const float* bk  = (const float*)d_in[5];
    const float* Wv  = (const float*)d_in[6];
    const float* bv  = (const float*)d_in[7];
    const float* Wpe = (const float*)d_in[8];
    const float* bpe = (const float*)d_in[9];
    const float* Wpd = (const float*)d_in[10];
    const float* bpd = (const float*)d_in[11];
    const float* Wa  = (const float*)d_in[12];
    const float* ba  = (const float*)d_in[13];
    const float* Wo  = (const float*)d_in[14];
    const float* bo  = (const float*)d_in[15];
    float* out = (float*)d_out;

    float* ws  = (float*)d_ws;
    float* qpe = ws;
    float* kpe = ws + (size_t)P_TOT * 64;
    float* vv  = ws + (size_t)2 * P_TOT * 64;
    int*   nbp = (int*)(ws + (size_t)3 * P_TOT * 64);           // 16384*16 ints
    int*   cstart = nbp + (size_t)P_TOT * KNB;                  // 4*513 ints
    float4* gpts = (float4*)(cstart + 4 * 513);                 // 16384 float4 (16B-aligned)

    proj_kernel<<<P_TOT / 4, 256, 0, stream>>>(x, pos, Wq, bq, Wk, bk, Wv, bv,
                                               Wpe, bpe, qpe, kpe, vv);
    grid_build<<<S_DIM, 1024, 0, stream>>>(pos, cstart, gpts);
    topk_kernel<<<P_TOT / 16, 1024, 0, stream>>>(pos, cstart, gpts, nbp);
    attn_kernel<<<P_TOT / 4, 256, 0, stream>>>(x, pos, Wpd, bpd, Wa, ba, Wo, bo,
                                               qpe, kpe, vv, nbp, out);
}

// Round 4
// 91.021 us; speedup vs baseline: 9.6039x; 1.2237x over previous
//
#include <hip/hip_runtime.h>
#include <hip/hip_bf16.h>

#define S_DIM 4
#define N_PTS 4096
#define P_TOT (S_DIM * N_PTS)   // 16384
#define HID 64
#define KNB 16

#define CELL_H 0.125f
#define CAP 352                  // per-wave candidate buffer (LDS)
#define PROJ_BLKS 1024           // 16 points per block

// ---------------- Kernel 1: fused projections + grid build ----------------
// blocks [0, PROJ_BLKS): qpe/kpe/v projections, 16 points per block.
// blocks [PROJ_BLKS, PROJ_BLKS+S_DIM): per-scene 8^3 cell grid build.
__global__ __launch_bounds__(1024) void pre_kernel(
    const float* __restrict__ x, const float* __restrict__ pos,
    const float* __restrict__ Wq, const float* __restrict__ bq,
    const float* __restrict__ Wk, const float* __restrict__ bk,
    const float* __restrict__ Wv, const float* __restrict__ bv,
    const float* __restrict__ Wpe, const float* __restrict__ bpe,
    float* __restrict__ qpe, float* __restrict__ kpe, float* __restrict__ vout,
    int* __restrict__ cell_start, float4* __restrict__ gpts)
{
    int tid = threadIdx.x;

    if (blockIdx.x < PROJ_BLKS) {
        // ---------------- projection path ----------------
        __shared__ float xs[16][64];
        __shared__ float ps[16][3];
        int h = tid & 63;
        int pl = tid >> 6;                   // 0..15
        int g = blockIdx.x * 16 + pl;

        xs[pl][h] = x[g * 64 + h];
        if (h < 3) ps[pl][h] = pos[g * 3 + h];
        __syncthreads();

        float aq = bq[h], ak = bk[h], av = bv[h];
        #pragma unroll
        for (int f = 0; f < 64; ++f) {
            float xf = xs[pl][f];
            aq = fmaf(xf, Wq[f * 64 + h], aq);
            ak = fmaf(xf, Wk[f * 64 + h], ak);
            av = fmaf(xf, Wv[f * 64 + h], av);
        }
        float pe = bpe[h];
        pe = fmaf(ps[pl][0], Wpe[0 * 64 + h], pe);
        pe = fmaf(ps[pl][1], Wpe[1 * 64 + h], pe);
        pe = fmaf(ps[pl][2], Wpe[2 * 64 + h], pe);

        qpe[g * 64 + h]  = aq + pe;
        kpe[g * 64 + h]  = ak + pe;
        vout[g * 64 + h] = av;
    } else {
        // ---------------- grid build path ----------------
        __shared__ int cnt[512];
        __shared__ int cur[512];
        __shared__ int start[513];

        int s = blockIdx.x - PROJ_BLKS;
        const float* psrc = pos + (size_t)s * N_PTS * 3;

        if (tid < 512) { cnt[tid] = 0; cur[tid] = 0; }
        __syncthreads();

        // thread t owns points 4t..4t+3 (3 coalesced float4 loads)
        const float4* g4 = (const float4*)psrc;
        float4 a = g4[tid * 3 + 0];
        float4 b = g4[tid * 3 + 1];
        float4 c4 = g4[tid * 3 + 2];
        float xx[4] = {a.x, a.w, b.z, c4.y};
        float yy[4] = {a.y, b.x, b.w, c4.z};
        float zz[4] = {a.z, b.y, c4.x, c4.w};
        int cell[4];
        #pragma unroll
        for (int k = 0; k < 4; ++k) {
            int cx = min(7, max(0, (int)(xx[k] * 8.0f)));
            int cy = min(7, max(0, (int)(yy[k] * 8.0f)));
            int cz = min(7, max(0, (int)(zz[k] * 8.0f)));
            cell[k] = (cx * 8 + cy) * 8 + cz;
            atomicAdd(&cnt[cell[k]], 1);
        }
        __syncthreads();

        // single-wave exclusive scan of 512 counts (8 per lane + shfl_up scan)
        if (tid < 64) {
            int c[8], pre[8], sum = 0;
            #pragma unroll
            for (int i = 0; i < 8; ++i) {
                c[i] = cnt[tid * 8 + i];
                pre[i] = sum;
                sum += c[i];
            }
            int inc = sum;
            #pragma unroll
            for (int off = 1; off < 64; off <<= 1) {
                int n = __shfl_up(inc, off, 64);
                if (tid >= off) inc += n;
            }
            int excl = inc - sum;
            #pragma unroll
            for (int i = 0; i < 8; ++i) start[tid * 8 + i] = excl + pre[i];
            if (tid == 63) start[512] = N_PTS;
        }
        __syncthreads();

        if (tid < 513) cell_start[s * 513 + tid] = start[tid];

        #pragma unroll
        for (int k = 0; k < 4; ++k) {
            int slot = start[cell[k]] + atomicAdd(&cur[cell[k]], 1);
            gpts[(size_t)s * N_PTS + slot] =
                make_float4(xx[k], yy[k], zz[k],
                            __uint_as_float((unsigned)(tid * 4 + k)));
        }
    }
}

// ---------------- Kernel 2: exact top-16 via grid ----------------
// One wave per query; 8 waves per block. Scan the (2D+1)^3 cell block around
// the query's cell, ballot-compact candidates with d < (D*h)^2 into LDS.
// Any point with d < (D*h)^2 lies within Chebyshev cell distance D, so if
// >=16 survive the compacted set contains the exact top-16; else D++.
// Keys (dist_bits<<32 | idx) are unique -> exact jax.lax.top_k ordering.
__global__ __launch_bounds__(512) void topk_kernel(
    const float* __restrict__ pos, const int* __restrict__ cell_start,
    const float4* __restrict__ gpts, int* __restrict__ nb)
{
    __shared__ unsigned long long buf[8][CAP];

    int tid = threadIdx.x;
    int wave = tid >> 6, lane = tid & 63;
    int g = blockIdx.x * 8 + wave;
    int s = g >> 12;
    const int* cs = cell_start + s * 513;
    const float4* gp = gpts + (size_t)s * N_PTS;
    unsigned long long* mybuf = buf[wave];

    float qx = pos[g * 3 + 0];
    float qy = pos[g * 3 + 1];
    float qz = pos[g * 3 + 2];
    int cx = min(7, max(0, (int)(qx * 8.0f)));
    int cy = min(7, max(0, (int)(qy * 8.0f)));
    int cz = min(7, max(0, (int)(qz * 8.0f)));
    cx = __builtin_amdgcn_readfirstlane(cx);
    cy = __builtin_amdgcn_readfirstlane(cy);
    cz = __builtin_amdgcn_readfirstlane(cz);

    unsigned long long lanemask_lt = (lane == 0) ? 0ull : (~0ull >> (64 - lane));

    int cnt = 0;
    int D = 1;
    while (true) {
        int xlo = max(cx - D, 0), xhi = min(cx + D, 7);
        int ylo = max(cy - D, 0), yhi = min(cy + D, 7);
        int zlo = max(cz - D, 0), zhi = min(cz + D, 7);
        bool full = (xlo == 0 && ylo == 0 && zlo == 0 &&
                     xhi == 7 && yhi == 7 && zhi == 7);
        float r = (float)D * CELL_H;
        float B = full ? __int_as_float(0x7f800000) : r * r;
        cnt = 0;
        for (int ix = xlo; ix <= xhi; ++ix) {
            for (int iy = ylo; iy <= yhi; ++iy) {
                int base = (ix * 8 + iy) * 8;
                int lo = __builtin_amdgcn_readfirstlane(cs[base + zlo]);
                int hi = __builtin_amdgcn_readfirstlane(cs[base + zhi + 1]);
                for (int bb = lo; bb < hi; bb += 64) {
                    int i = bb + lane;
                    bool act = i < hi;
                    float4 p = gp[act ? i : lo];
                    float dx = qx - p.x, dy = qy - p.y, dz = qz - p.z;
                    float d = fmaf(dx, dx, fmaf(dy, dy, dz * dz));
                    bool pred = act && (d < B);
                    unsigned long long m = __ballot(pred);
                    if (pred) {
                        int slot = cnt + __popcll(m & lanemask_lt);
                        if (slot < CAP)
                            mybuf[slot] =
                                ((unsigned long long)__float_as_uint(d) << 32) |
                                (unsigned long long)__float_as_uint(p.w);
                    }
                    cnt += __popcll(m);
                }
            }
        }
        if (cnt >= KNB || full) break;
        ++D;
    }
    cnt = min(cnt, CAP);

    // rank-count selection: rank = #{keys < mine}; unique keys -> exact order
    for (int bb = 0; bb < cnt; bb += 64) {
        int slot = bb + lane;
        unsigned long long my = (slot < cnt) ? mybuf[slot] : ~0ull;
        int rank = 0;
        for (int j = 0; j < cnt; ++j)
            rank += (mybuf[j] < my) ? 1 : 0;
        if (slot < cnt && rank < KNB)
            nb[(size_t)g * KNB + rank] = (int)(unsigned)(my & 0xFFFFFFFFull);
    }
}

__device__ __forceinline__ float readlane_f(float v, int lane) {
    return __uint_as_float(__builtin_amdgcn_readlane(__float_as_uint(v), lane));
}

// ---------------- Kernel 3: neighbor attention + output proj ----------------
// One wave per point, lane = h. Logit reduction uses a merged log-tree:
// 16 vectors reduced with 31 shfl; logits end distributed one per 4-lane
// group with k = rev4(lane>>2). Softmax: 1 exp/lane, 4-shfl max/sum.
// Broadcasts (attn weights, Wo projection) via v_readlane (no DS pipe).
__global__ __launch_bounds__(256) void attn_kernel(
    const float* __restrict__ x, const float* __restrict__ pos,
    const float* __restrict__ Wpd, const float* __restrict__ bpd,
    const float* __restrict__ Wa, const float* __restrict__ ba,
    const float* __restrict__ Wo, const float* __restrict__ bo,
    const float* __restrict__ qpe, const float* __restrict__ kpe,
    const float* __restrict__ v, const int* __restrict__ nb,
    float* __restrict__ out)
{
    int tid = threadIdx.x;
    int h = tid & 63;
    int w = tid >> 6;
    int g = blockIdx.x * 4 + w;
    int sbase = (g >> 12) << 12;

    float qv = qpe[g * 64 + h];
    float wh = qv * Wa[h] * 0.125f;   // / sqrt(64)

    float xn = pos[g * 3 + 0];
    float yn = pos[g * 3 + 1];
    float zn = pos[g * 3 + 2];
    float wpd0 = Wpd[0 * 64 + h], wpd1 = Wpd[1 * 64 + h], wpd2 = Wpd[2 * 64 + h];
    float bpdh = bpd[h];

    int jidx[KNB];
    float t[KNB];
    #pragma unroll
    for (int k = 0; k < KNB; ++k) {
        int jj = sbase + nb[g * KNB + k];
        jj = __builtin_amdgcn_readfirstlane(jj);
        jidx[k] = jj;
        float rx = pos[jj * 3 + 0] - xn;
        float ry = pos[jj * 3 + 1] - yn;
        float rz = pos[jj * 3 + 2] - zn;
        float pd = fmaf(rx, wpd0, fmaf(ry, wpd1, fmaf(rz, wpd2, bpdh)));
        t[k] = wh * (kpe[jj * 64 + h] + pd);
    }

    // merged log-tree reduction: level l merges pairs, select on lane bit (5-l)
    #pragma unroll
    for (int kk = 0; kk < 8; ++kk) {
        float a = t[2 * kk]     + __shfl_xor(t[2 * kk],     32, 64);
        float b = t[2 * kk + 1] + __shfl_xor(t[2 * kk + 1], 32, 64);
        t[kk] = (h & 32) ? b : a;
    }
    #pragma unroll
    for (int kk = 0; kk < 4; ++kk) {
        float a = t[2 * kk]     + __shfl_xor(t[2 * kk],     16, 64);
        float b = t[2 * kk + 1] + __shfl_xor(t[2 * kk + 1], 16, 64);
        t[kk] = (h & 16) ? b : a;
    }
    #pragma unroll
    for (int kk = 0; kk < 2; ++kk) {
        float a = t[2 * kk]     + __shfl_xor(t[2 * kk],     8, 64);
        float b = t[2 * kk + 1] + __shfl_xor(t[2 * kk + 1], 8, 64);
        t[kk] = (h & 8) ? b : a;
    }
    {
        float a = t[0] + __shfl_xor(t[0], 4, 64);
        float b = t[1] + __shfl_xor(t[1], 4, 64);
        t[0] = (h & 4) ? b : a;
    }
    float r = t[0];
    r += __shfl_xor(r, 2, 64);
    r += __shfl_xor(r, 1, 64);
    // lane holds logit of k = rev4(lane>>2): kbits = lane[2],lane[3],lane[4],lane[5]

    float lg = r + ba[0];
    float mx = lg;
    mx = fmaxf(mx, __shfl_xor(mx, 4, 64));
    mx = fmaxf(mx, __shfl_xor(mx, 8, 64));
    mx = fmaxf(mx, __shfl_xor(mx, 16, 64));
    mx = fmaxf(mx, __shfl_xor(mx, 32, 64));
    float e = expf(lg - mx);
    float sm = e;
    sm += __shfl_xor(sm, 4, 64);
    sm += __shfl_xor(sm, 8, 64);
    sm += __shfl_xor(sm, 16, 64);
    sm += __shfl_xor(sm, 32, 64);
    float wk_mine = e * (1.0f / sm);

    // PV: broadcast w_k from lane rev4(k)*4 (rev4 is an involution)
    const int rev[KNB] = {0, 8, 4, 12, 2, 10, 6, 14, 1, 9, 5, 13, 3, 11, 7, 15};
    float oh = 0.f;
    #pragma unroll
    for (int k = 0; k < KNB; ++k) {
        float wk = readlane_f(wk_mine, rev[k] << 2);
        oh = fmaf(wk, v[jidx[k] * 64 + h], oh);
    }

    // y_f = bo[f] + sum_h oh[h] * Wo[h][f]   (lane == f), via readlane
    float y = bo[h];
    #pragma unroll
    for (int hh = 0; hh < 64; ++hh) {
        float o = readlane_f(oh, hh);
        y = fmaf(o, Wo[hh * 64 + h], y);
    }

    // tanh-approx GELU (JAX default approximate=True)
    float t3 = y + 0.044715f * y * y * y;
    float ge = 0.5f * y * (1.0f + tanhf(0.7978845608028654f * t3));

    out[g * 64 + h] = x[g * 64 + h] + ge;
}

extern "C" void kernel_launch(void* const* d_in, const int* in_sizes, int n_in,
                              void* d_out, int out_size, void* d_ws, size_t ws_size,
                              hipStream_t stream) {
    const float* x   = (const float*)d_in[0];
    const float* pos = (const float*)d_in[1];
    const float* Wq  = (const float*)d_in[2];
    const float* bq  = (const float*)d_in[3];
    const float* Wk  = (const float*)d_in[4];
    const float* bk  = (const float*)d_in[5];
    const float* Wv  = (const float*)d_in[6];
    const float* bv  = (const float*)d_in[7];
    const float* Wpe = (const float*)d_in[8];
    const float* bpe = (const float*)d_in[9];
    const float* Wpd = (const float*)d_in[10];
    const float* bpd = (const float*)d_in[11];
    const float* Wa  = (const float*)d_in[12];
    const float* ba  = (const float*)d_in[13];
    const float* Wo  = (const float*)d_in[14];
    const float* bo  = (const float*)d_in[15];
    float* out = (float*)d_out;

    float* ws  = (float*)d_ws;
    float* qpe = ws;
    float* kpe = ws + (size_t)P_TOT * 64;
    float* vv  = ws + (size_t)2 * P_TOT * 64;
    int*   nbp = (int*)(ws + (size_t)3 * P_TOT * 64);           // 16384*16 ints
    int*   cstart = nbp + (size_t)P_TOT * KNB;                  // 4*513 ints
    float4* gpts = (float4*)(cstart + 4 * 513 + 3);             // 16B-aligned

    pre_kernel<<<PROJ_BLKS + S_DIM, 1024, 0, stream>>>(
        x, pos, Wq, bq, Wk, bk, Wv, bv, Wpe, bpe, qpe, kpe, vv, cstart, gpts);
    topk_kernel<<<P_TOT / 8, 512, 0, stream>>>(pos, cstart, gpts, nbp);
    attn_kernel<<<P_TOT / 4, 256, 0, stream>>>(x, pos, Wpd, bpd, Wa, ba, Wo, bo,
                                               qpe, kpe, vv, nbp, out);
}